// Round 7
// baseline (418.376 us; speedup 1.0000x reference)
//
#include <hip/hip_runtime.h>
#include <hip/hip_fp16.h>

typedef unsigned short u16;
typedef unsigned int u32;
typedef __bf16 bf16x8 __attribute__((ext_vector_type(8)));
typedef float f32x4 __attribute__((ext_vector_type(4)));

// N_NODES=131072, IN_CHANNELS=256, NUM_PROJ=256, NUM_QUANT=256, NUM_GRAPHS=256
// nodes_per_graph = 512; scale = sqrt(256*256) = 256.

__device__ __forceinline__ u16 f2bf(float f) {
  union { float f; u32 u; } v; v.f = f;
  u32 r = (v.u + 0x7FFFu + ((v.u >> 16) & 1u)) >> 16;  // RNE
  return (u16)r;
}

// pack two fp32 -> packed bf16 pair (a low, b high), RNE — single VOP3
__device__ __forceinline__ u32 cvtpk(float a, float b) {
  u32 r; asm("v_cvt_pk_bf16_f32 %0, %1, %2" : "=v"(r) : "v"(a), "v"(b));
  return r;
}

// pack two fp32 -> packed fp16 pair, RNE (matches __float2half semantics)
__device__ __forceinline__ u32 pkh(float a, float b) {
  return (u32)__half_as_ushort(__float2half(a)) |
         ((u32)__half_as_ushort(__float2half(b)) << 16);
}

// v_perm_b32: sel byte<4 -> S1 bytes, >=4 -> S0 bytes
__device__ __forceinline__ u32 vperm(u32 s0, u32 s1, u32 sel) {
  u32 r; asm("v_perm_b32 %0, %1, %2, %3" : "=v"(r) : "v"(s0), "v"(s1), "s"(sel));
  return r;
}

// packed fp16 min/max (1 VOP3P each, both halves)
__device__ __forceinline__ u32 pkmin(u32 a, u32 b) {
  u32 r; asm("v_pk_min_f16 %0, %1, %2" : "=v"(r) : "v"(a), "v"(b)); return r;
}
__device__ __forceinline__ u32 pkmax(u32 a, u32 b) {
  u32 r; asm("v_pk_max_f16 %0, %1, %2" : "=v"(r) : "v"(a), "v"(b)); return r;
}

// cross-lane exchange: DPP (VALU pipe, free of DS) / ds_swizzle / bpermute
template <int CTRL> __device__ __forceinline__ u32 xdpp(u32 x) {
  return (u32)__builtin_amdgcn_mov_dpp((int)x, CTRL, 0xF, 0xF, true);
}
template <int IMM> __device__ __forceinline__ u32 xswz(u32 x) {
  return (u32)__builtin_amdgcn_ds_swizzle((int)x, IMM);
}
#define EX_X1(x)  xdpp<0xB1>(x)      /* quad_perm [1,0,3,2]  = xor 1  */
#define EX_X2(x)  xdpp<0x4E>(x)      /* quad_perm [2,3,0,1]  = xor 2  */
#define EX_F3(x)  xdpp<0x1B>(x)      /* quad_perm [3,2,1,0]  = xor 3  */
#define EX_F7(x)  xdpp<0x141>(x)     /* half_mirror          = xor 7  */
#define EX_F15(x) xdpp<0x140>(x)     /* row_mirror           = xor 15 */
#define EX_X8(x)  xdpp<0x128>(x)     /* row_ror:8            = xor 8  */
#define EX_X4(x)  xswz<0x101F>(x)    /* swizzle xor 4  */
#define EX_X16(x) xswz<0x401F>(x)    /* swizzle xor 16 */
#define EX_F31(x) xswz<0x7C1F>(x)    /* swizzle xor 31 */
#define EX_F63(x) ((u32)__shfl_xor((int)(x), 63, 64))

// ---------------- Kernel 0: proj (k-major fp32) -> projT[p][k] bf16 ----------------
__global__ __launch_bounds__(256) void transpose_proj(const float* __restrict__ proj,
                                                      u16* __restrict__ projT) {
  const int k = blockIdx.x;
  const int p = threadIdx.x;
  projT[(size_t)p * 256 + k] = f2bf(proj[(size_t)k * 256 + p]);
}

// ---------------- Fused kernel: TWO blocks per graph (p-halves) --------------------
// Grid 512: block = (g = bid&255, h = bid>>8). LDS 49,664 B; per-thread regs kept
// under the 64-VGPR 2-blocks/CU cap by NOT holding both node-tiles' A-frags:
// x is re-read per slice per t-half (L3-resident — R5 FETCH showed x served from
// Infinity Cache), so only a_t[8] (32 VGPR) + one acc are live. 8 waves/SIMD hides
// the bitonic net's dependent-chain + DS latency; independent blocks overlap phases.
__global__ __launch_bounds__(1024, 8) void fused_swe(const float* __restrict__ x,
                                                     const u16* __restrict__ projT,
                                                     const float* __restrict__ cw,
                                                     float* __restrict__ out) {
  // LDS: [0, 16384)      Ps: 32 rows x 512 B (256 bf16), 16B segs XOR-swizzled
  //      [16384, 49664)  res: u32[32][260]  (row = p_local, 512 fp16 nodes + pad)
  extern __shared__ __attribute__((aligned(16))) char lds[];
  u32* res = (u32*)(lds + 16384);

  const int tid = threadIdx.x;
  const int lane = tid & 63;
  const int w = tid >> 6;            // wave 0..15
  const int g = blockIdx.x & 255;    // graph
  const int h = blockIdx.x >> 8;     // p-half 0..1
  const int quad = lane >> 4;        // 0..3
  const int m16 = lane & 15;

  for (int sl = 0; sl < 4; ++sl) {
    const int pbase = h * 128 + sl * 32;  // global p of this slice's p_local 0

    // ---- P1: stage projT slice [32 p][256 k] bf16, 16B-seg XOR swizzle
    // 32 rows x 32 segs of 16B = 16 KiB = 1024 threads x 1 uint4 (full rows)
    {
      const int row = tid >> 5;   // p_local 0..31
      const int seg = tid & 31;   // 16B segment 0..31 (8 bf16 each)
      uint4 d = *(const uint4*)(projT + (size_t)(pbase + row) * 256 + seg * 8);
      *(uint4*)(lds + row * 512 + ((seg ^ (row & 7)) * 16)) = d;
    }
    __syncthreads();

    // ---- P2: GEMM  C[node][p] ; A-frag (re)loaded per t-half from x (L3-hot),
    //          B-frag from swizzled LDS. Only a_t[8] (32 VGPR) live at a time.
#pragma unroll
    for (int t = 0; t < 2; ++t) {
      bf16x8 at[8];
      const float* ap = x + (size_t)(g * 512 + w * 32 + t * 16 + m16) * 256 + quad * 8;
#pragma unroll
      for (int ks = 0; ks < 8; ++ks) {
        float4 f0 = *(const float4*)(ap + ks * 32);
        float4 f1 = *(const float4*)(ap + ks * 32 + 4);
        u32 pk4[4] = { cvtpk(f0.x, f0.y), cvtpk(f0.z, f0.w),
                       cvtpk(f1.x, f1.y), cvtpk(f1.z, f1.w) };
        at[ks] = *(const bf16x8*)pk4;
      }
#pragma unroll
      for (int nt = 0; nt < 2; ++nt) {
        const int prow = nt * 16 + m16;     // p_local 0..31
        const int rx = (prow & 7) << 4;
        const char* pb = lds + prow * 512;
        f32x4 acc = {0.f, 0.f, 0.f, 0.f};
#pragma unroll
        for (int ks = 0; ks < 8; ++ks) {
          bf16x8 bfrag = *(const bf16x8*)(pb + (((ks * 64) | (quad * 16)) ^ rx));
          acc = __builtin_amdgcn_mfma_f32_16x16x32_bf16(at[ks], bfrag, acc, 0, 0, 0);
        }
        // C row = node = w*32 + t*16 + quad*4 + r ; col = p_local = prow
        const int wb = prow * 260 + w * 16 + t * 8 + quad * 2;
        res[wb]     = pkh(acc[0], acc[1]);
        res[wb + 1] = pkh(acc[2], acc[3]);
      }
    }
    __syncthreads();

    // ---- P3/P4: one dual-packed bitonic sort per wave (p = w lo, p = w+16 hi)
    {
      u32* ra = res + w * 260;
      u32* rb = res + (w + 16) * 260;
      uint4 a4 = *(const uint4*)(ra + lane * 4);
      uint4 b4 = *(const uint4*)(rb + lane * 4);
      u32 v[8];
      v[0] = vperm(b4.x, a4.x, 0x05040100u); v[1] = vperm(b4.x, a4.x, 0x07060302u);
      v[2] = vperm(b4.y, a4.y, 0x05040100u); v[3] = vperm(b4.y, a4.y, 0x07060302u);
      v[4] = vperm(b4.z, a4.z, 0x05040100u); v[5] = vperm(b4.z, a4.z, 0x07060302u);
      v[6] = vperm(b4.w, a4.w, 0x05040100u); v[7] = vperm(b4.w, a4.w, 0x07060302u);

#define CE(i, j) { u32 mn_ = pkmin(v[i], v[j]); u32 mx_ = pkmax(v[i], v[j]); v[i] = mn_; v[j] = mx_; }
#define INTRA3 \
  CE(0,4) CE(1,5) CE(2,6) CE(3,7) \
  CE(0,2) CE(1,3) CE(4,6) CE(5,7) \
  CE(0,1) CE(2,3) CE(4,5) CE(6,7)

#define FLIPP(EX, lowbit) { \
    const bool low_ = (lane & (lowbit)) == 0; \
    u32 t_[8]; \
    _Pragma("unroll") for (int r = 0; r < 8; ++r) t_[r] = EX(v[7 - r]); \
    _Pragma("unroll") for (int r = 0; r < 8; ++r) { \
      u32 mn_ = pkmin(v[r], t_[r]); u32 mx_ = pkmax(v[r], t_[r]); \
      v[r] = low_ ? mn_ : mx_; } }

#define XCROSSP(EX, lm) { \
    const bool low_ = (lane & (lm)) == 0; \
    _Pragma("unroll") for (int r = 0; r < 8; ++r) { \
      u32 t_ = EX(v[r]); \
      u32 mn_ = pkmin(v[r], t_); u32 mx_ = pkmax(v[r], t_); \
      v[r] = low_ ? mn_ : mx_; } }

      // S=2
      CE(0,1) CE(2,3) CE(4,5) CE(6,7)
      // S=4
      CE(0,3) CE(1,2) CE(4,7) CE(5,6)
      CE(0,1) CE(2,3) CE(4,5) CE(6,7)
      // S=8
      CE(0,7) CE(1,6) CE(2,5) CE(3,4)
      CE(0,2) CE(1,3) CE(4,6) CE(5,7)
      CE(0,1) CE(2,3) CE(4,5) CE(6,7)
      // S=16
      FLIPP(EX_X1, 1)  INTRA3
      // S=32
      FLIPP(EX_F3, 2)  XCROSSP(EX_X1, 1)  INTRA3
      // S=64
      FLIPP(EX_F7, 4)  XCROSSP(EX_X2, 2) XCROSSP(EX_X1, 1)  INTRA3
      // S=128
      FLIPP(EX_F15, 8) XCROSSP(EX_X4, 4) XCROSSP(EX_X2, 2) XCROSSP(EX_X1, 1)  INTRA3
      // S=256
      FLIPP(EX_F31, 16) XCROSSP(EX_X8, 8) XCROSSP(EX_X4, 4) XCROSSP(EX_X2, 2) XCROSSP(EX_X1, 1)  INTRA3
      // S=512
      FLIPP(EX_F63, 32) XCROSSP(EX_X16, 16) XCROSSP(EX_X8, 8) XCROSSP(EX_X4, 4) XCROSSP(EX_X2, 2) XCROSSP(EX_X1, 1)  INTRA3

#undef CE
#undef INTRA3
#undef FLIPP
#undef XCROSSP

      // in-place park: sorted index i = lane*8 + r ; i<256 -> row w, else row w+16
      u32* pp = (lane < 32) ? (ra + lane * 8) : (rb + lane * 8 - 256);
      *(uint4*)pp       = (uint4){v[0], v[1], v[2], v[3]};
      *(uint4*)(pp + 4) = (uint4){v[4], v[5], v[6], v[7]};
    }
    __syncthreads();

    // ---- P5: quantile select + coalesced write (32 p-cols of this slice)
#pragma unroll
    for (int it = 0; it < 8; ++it) {
      const int linear = it * 1024 + tid;  // 0..8191
      const int q = linear >> 5;
      const int pc = linear & 31;          // p_local in slice
      const int iq = (int)floorf(cw[q] * 511.0f);
      const int dd = pc & 15;
      const u32 val = res[dd * 260 + ((iq >= 256) ? (iq + 3904) : iq)];  // 3904 = 16*260-256
      const u16 hh = (pc & 16) ? (u16)(val >> 16) : (u16)(val & 0xFFFF);
      __half_raw hr; hr.x = hh;
      out[(size_t)g * 65536 + (size_t)q * 256 + pbase + pc] =
          __half2float(__half(hr)) * 0.00390625f;
    }
    // next slice: P1 touches Ps only; the sync after P1 orders P5 reads vs P2 writes
  }
}

extern "C" void kernel_launch(void* const* d_in, const int* in_sizes, int n_in,
                              void* d_out, int out_size, void* d_ws, size_t ws_size,
                              hipStream_t stream) {
  const float* x    = (const float*)d_in[0];  // (131072, 256) fp32
  const float* proj = (const float*)d_in[1];  // (256, 256) fp32
  const float* cw   = (const float*)d_in[2];  // (256,) fp32
  float* out = (float*)d_out;                 // (256, 65536) fp32

  u16* projT = (u16*)d_ws;                    // 128 KiB

  transpose_proj<<<256, 256, 0, stream>>>(proj, projT);
  fused_swe<<<512, 1024, 49664, stream>>>(x, projT, cw, out);
}

// Round 8
// 293.411 us; speedup vs baseline: 1.4259x; 1.4259x over previous
//
#include <hip/hip_runtime.h>
#include <hip/hip_fp16.h>

typedef unsigned short u16;
typedef unsigned int u32;
typedef __bf16 bf16x8 __attribute__((ext_vector_type(8)));
typedef float f32x4 __attribute__((ext_vector_type(4)));

// N_NODES=131072, IN_CHANNELS=256, NUM_PROJ=256, NUM_QUANT=256, NUM_GRAPHS=256
// nodes_per_graph = 512; scale = sqrt(256*256) = 256.

__device__ __forceinline__ u16 f2bf(float f) {
  union { float f; u32 u; } v; v.f = f;
  u32 r = (v.u + 0x7FFFu + ((v.u >> 16) & 1u)) >> 16;  // RNE
  return (u16)r;
}

// pack two fp32 -> packed bf16 pair (a low, b high), RNE — single VOP3
__device__ __forceinline__ u32 cvtpk(float a, float b) {
  u32 r; asm("v_cvt_pk_bf16_f32 %0, %1, %2" : "=v"(r) : "v"(a), "v"(b));
  return r;
}

// pack two fp32 -> packed fp16 pair, RNE (matches __float2half semantics)
__device__ __forceinline__ u32 pkh(float a, float b) {
  return (u32)__half_as_ushort(__float2half(a)) |
         ((u32)__half_as_ushort(__float2half(b)) << 16);
}

// v_perm_b32: sel byte<4 -> S1 bytes, >=4 -> S0 bytes
__device__ __forceinline__ u32 vperm(u32 s0, u32 s1, u32 sel) {
  u32 r; asm("v_perm_b32 %0, %1, %2, %3" : "=v"(r) : "v"(s0), "v"(s1), "s"(sel));
  return r;
}

// packed fp16 min/max (1 VOP3P each, both halves)
__device__ __forceinline__ u32 pkmin(u32 a, u32 b) {
  u32 r; asm("v_pk_min_f16 %0, %1, %2" : "=v"(r) : "v"(a), "v"(b)); return r;
}
__device__ __forceinline__ u32 pkmax(u32 a, u32 b) {
  u32 r; asm("v_pk_max_f16 %0, %1, %2" : "=v"(r) : "v"(a), "v"(b)); return r;
}

// cross-lane exchange: DPP (VALU pipe, free of DS) / ds_swizzle / bpermute
template <int CTRL> __device__ __forceinline__ u32 xdpp(u32 x) {
  return (u32)__builtin_amdgcn_mov_dpp((int)x, CTRL, 0xF, 0xF, true);
}
template <int IMM> __device__ __forceinline__ u32 xswz(u32 x) {
  return (u32)__builtin_amdgcn_ds_swizzle((int)x, IMM);
}
#define EX_X1(x)  xdpp<0xB1>(x)      /* quad_perm [1,0,3,2]  = xor 1  */
#define EX_X2(x)  xdpp<0x4E>(x)      /* quad_perm [2,3,0,1]  = xor 2  */
#define EX_F3(x)  xdpp<0x1B>(x)      /* quad_perm [3,2,1,0]  = xor 3  */
#define EX_F7(x)  xdpp<0x141>(x)     /* half_mirror          = xor 7  */
#define EX_F15(x) xdpp<0x140>(x)     /* row_mirror           = xor 15 */
#define EX_X8(x)  xdpp<0x128>(x)     /* row_ror:8            = xor 8  */
#define EX_X4(x)  xswz<0x101F>(x)    /* swizzle xor 4  */
#define EX_X16(x) xswz<0x401F>(x)    /* swizzle xor 16 */
#define EX_F31(x) xswz<0x7C1F>(x)    /* swizzle xor 31 */
#define EX_F63(x) ((u32)__shfl_xor((int)(x), 63, 64))

// ---------------- Kernel 0: proj (k-major fp32) -> projT[p][k] bf16 ----------------
__global__ __launch_bounds__(256) void transpose_proj(const float* __restrict__ proj,
                                                      u16* __restrict__ projT) {
  const int k = blockIdx.x;
  const int p = threadIdx.x;
  projT[(size_t)p * 256 + k] = f2bf(proj[(size_t)k * 256 + p]);
}

// bitonic network pieces (operate on u32 v[8] of packed fp16 pairs; `lane` in scope)
#define CE(i, j) { u32 mn_ = pkmin(v[i], v[j]); u32 mx_ = pkmax(v[i], v[j]); v[i] = mn_; v[j] = mx_; }
#define INTRA3 \
  CE(0,4) CE(1,5) CE(2,6) CE(3,7) \
  CE(0,2) CE(1,3) CE(4,6) CE(5,7) \
  CE(0,1) CE(2,3) CE(4,5) CE(6,7)
#define FLIPP(EX, lowbit) { \
    const bool low_ = (lane & (lowbit)) == 0; \
    u32 t_[8]; \
    _Pragma("unroll") for (int r = 0; r < 8; ++r) t_[r] = EX(v[7 - r]); \
    _Pragma("unroll") for (int r = 0; r < 8; ++r) { \
      u32 mn_ = pkmin(v[r], t_[r]); u32 mx_ = pkmax(v[r], t_[r]); \
      v[r] = low_ ? mn_ : mx_; } }
#define XCROSSP(EX, lm) { \
    const bool low_ = (lane & (lm)) == 0; \
    _Pragma("unroll") for (int r = 0; r < 8; ++r) { \
      u32 t_ = EX(v[r]); \
      u32 mn_ = pkmin(v[r], t_); u32 mx_ = pkmax(v[r], t_); \
      v[r] = low_ ? mn_ : mx_; } }

// network split into 5 sections so GEMM chunks can interleave between them
#define NETSEC0 \
  CE(0,1) CE(2,3) CE(4,5) CE(6,7) \
  CE(0,3) CE(1,2) CE(4,7) CE(5,6) \
  CE(0,1) CE(2,3) CE(4,5) CE(6,7) \
  CE(0,7) CE(1,6) CE(2,5) CE(3,4) \
  CE(0,2) CE(1,3) CE(4,6) CE(5,7) \
  CE(0,1) CE(2,3) CE(4,5) CE(6,7) \
  FLIPP(EX_X1, 1)  INTRA3
#define NETSEC1 \
  FLIPP(EX_F3, 2)  XCROSSP(EX_X1, 1)  INTRA3 \
  FLIPP(EX_F7, 4)  XCROSSP(EX_X2, 2) XCROSSP(EX_X1, 1)  INTRA3
#define NETSEC2 \
  FLIPP(EX_F15, 8) XCROSSP(EX_X4, 4) XCROSSP(EX_X2, 2) XCROSSP(EX_X1, 1)  INTRA3
#define NETSEC3 \
  FLIPP(EX_F31, 16) XCROSSP(EX_X8, 8) XCROSSP(EX_X4, 4) XCROSSP(EX_X2, 2) XCROSSP(EX_X1, 1)  INTRA3
#define NETSEC4 \
  FLIPP(EX_F63, 32) XCROSSP(EX_X16, 16) XCROSSP(EX_X8, 8) XCROSSP(EX_X4, 4) XCROSSP(EX_X2, 2) XCROSSP(EX_X1, 1)  INTRA3

// one GEMM quadrant of slice s+1: 8 ds_read + 8 MFMA + 2 pk-stores (interleaves w/ NETSEC)
#define GEMMSEC(t, nt) { \
  const int prow_ = (nt) * 16 + m16; \
  const int rx_ = (prow_ & 7) << 4; \
  const char* pb_ = PsN + prow_ * 512; \
  f32x4 acc_ = {0.f, 0.f, 0.f, 0.f}; \
  _Pragma("unroll") for (int ks_ = 0; ks_ < 8; ++ks_) { \
    bf16x8 bf_ = *(const bf16x8*)(pb_ + (((ks_ * 64) | (quad * 16)) ^ rx_)); \
    acc_ = __builtin_amdgcn_mfma_f32_16x16x32_bf16(a[t][ks_], bf_, acc_, 0, 0, 0); \
  } \
  const int wb_ = prow_ * 260 + w * 16 + (t) * 8 + quad * 2; \
  resN[wb_]     = pkh(acc_[0], acc_[1]); \
  resN[wb_ + 1] = pkh(acc_[2], acc_[3]); }

#define SORTLOAD \
  uint4 a4 = *(const uint4*)(ra + lane * 4); \
  uint4 b4 = *(const uint4*)(rb + lane * 4); \
  u32 v[8]; \
  v[0] = vperm(b4.x, a4.x, 0x05040100u); v[1] = vperm(b4.x, a4.x, 0x07060302u); \
  v[2] = vperm(b4.y, a4.y, 0x05040100u); v[3] = vperm(b4.y, a4.y, 0x07060302u); \
  v[4] = vperm(b4.z, a4.z, 0x05040100u); v[5] = vperm(b4.z, a4.z, 0x07060302u); \
  v[6] = vperm(b4.w, a4.w, 0x05040100u); v[7] = vperm(b4.w, a4.w, 0x07060302u);

#define PARK { \
  u32* pp_ = (lane < 32) ? (ra + lane * 8) : (rb + lane * 8 - 256); \
  *(uint4*)pp_       = (uint4){v[0], v[1], v[2], v[3]}; \
  *(uint4*)(pp_ + 4) = (uint4){v[4], v[5], v[6], v[7]}; }

#define SELECT(sl) { \
  _Pragma("unroll") for (int it_ = 0; it_ < 8; ++it_) { \
    const int linear_ = it_ * 1024 + tid; \
    const int q_ = linear_ >> 5; \
    const int pc_ = linear_ & 31; \
    const int iq_ = (int)floorf(cw[q_] * 511.0f); \
    const int dd_ = pc_ & 15; \
    const u32 val_ = resC[dd_ * 260 + ((iq_ >= 256) ? (iq_ + 3904) : iq_)]; \
    const u16 hh_ = (pc_ & 16) ? (u16)(val_ >> 16) : (u16)(val_ & 0xFFFF); \
    __half_raw hr_; hr_.x = hh_; \
    out[(size_t)g * 65536 + (size_t)q_ * 256 + (sl) * 32 + pc_] = \
        __half2float(__half(hr_)) * 0.00390625f; } }

// ---------------- Fused kernel: one block per graph, slice-pipelined ---------------
// 8 slices of 32 p. Steady state: slice s's register bitonic network (VALU/DPP)
// interleaved in-stream with slice s+1's GEMM (ds_read+MFMA) — separate pipes
// overlap within each wave. Ps double-buffered (2x16K), res double-buffered
// (2x33.3K): LDS 99,328 B -> 1 block/CU, 4 waves/SIMD, reg cap 128 (no spill).
__global__ __launch_bounds__(1024, 4) void fused_swe(const float* __restrict__ x,
                                                     const u16* __restrict__ projT,
                                                     const float* __restrict__ cw,
                                                     float* __restrict__ out) {
  // LDS: Ps[0] @0, Ps[1] @16384 (32 rows x 512 B, 16B segs XOR-swizzled)
  //      res[0] @32768, res[1] @66048 (u32[32][260])
  extern __shared__ __attribute__((aligned(16))) char lds[];

  const int tid = threadIdx.x;
  const int lane = tid & 63;
  const int w = tid >> 6;        // wave 0..15
  const int g = blockIdx.x;      // graph
  const int quad = lane >> 4;    // 0..3
  const int m16 = lane & 15;

  // ---- prologue: x[g] node-rows for this wave -> bf16 regs (persistent, 64 VGPR)
  bf16x8 a[2][8];
#pragma unroll
  for (int t = 0; t < 2; ++t) {
    const float* ap = x + (size_t)(g * 512 + w * 32 + t * 16 + m16) * 256 + quad * 8;
#pragma unroll
    for (int ks = 0; ks < 8; ++ks) {
      float4 f0 = *(const float4*)(ap + ks * 32);
      float4 f1 = *(const float4*)(ap + ks * 32 + 4);
      u32 pk4[4] = { cvtpk(f0.x, f0.y), cvtpk(f0.z, f0.w),
                     cvtpk(f1.x, f1.y), cvtpk(f1.z, f1.w) };
      a[t][ks] = *(const bf16x8*)pk4;
    }
  }

  // ---- prologue: stage slice 0 into Ps[0]; GEMM(0) -> res[0]
  {
    const int row = tid >> 5;
    const int seg = tid & 31;
    uint4 d = *(const uint4*)(projT + (size_t)row * 256 + seg * 8);
    *(uint4*)(lds + row * 512 + ((seg ^ (row & 7)) * 16)) = d;
  }
  __syncthreads();
  {
    u32* resN = (u32*)(lds + 32768);
    const char* PsN = lds;
    GEMMSEC(0, 0) GEMMSEC(0, 1) GEMMSEC(1, 0) GEMMSEC(1, 1)
  }
  __syncthreads();

  // ---- steady state: network(s) || GEMM(s+1), s = 0..6
  for (int s = 0; s < 7; ++s) {
    u32* resC = (u32*)(lds + 32768 + (size_t)(s & 1) * 33280);
    u32* resN = (u32*)(lds + 32768 + (size_t)((s + 1) & 1) * 33280);
    const char* PsN = lds + ((s + 1) & 1) * 16384;
    u32* ra = resC + w * 260;
    u32* rb = resC + (w + 16) * 260;

    SORTLOAD                      // slice s columns -> regs; res[s&1] now free of readers
    {                             // stage slice s+1 into Ps[(s+1)&1]
      const int row = tid >> 5;
      const int seg = tid & 31;
      uint4 d = *(const uint4*)(projT + (size_t)((s + 1) * 32 + row) * 256 + seg * 8);
      *(uint4*)((char*)PsN + row * 512 + ((seg ^ (row & 7)) * 16)) = d;
    }
    __syncthreads();              // Ps staged; select(s-1) done before GEMM(s+1) reuses res

    NETSEC0 GEMMSEC(0, 0)
    NETSEC1 GEMMSEC(0, 1)
    NETSEC2 GEMMSEC(1, 0)
    NETSEC3 GEMMSEC(1, 1)
    NETSEC4

    PARK                          // sorted slice s -> res[s&1] (own columns only)
    __syncthreads();              // park + GEMM(s+1) res-writes visible
    SELECT(s)
  }

  // ---- tail: slice 7 (no GEMM to overlap)
  {
    u32* resC = (u32*)(lds + 32768 + 33280);  // 7&1 = 1
    u32* ra = resC + w * 260;
    u32* rb = resC + (w + 16) * 260;
    SORTLOAD
    __syncthreads();
    NETSEC0 NETSEC1 NETSEC2 NETSEC3 NETSEC4
    PARK
    __syncthreads();
    SELECT(7)
  }
}

extern "C" void kernel_launch(void* const* d_in, const int* in_sizes, int n_in,
                              void* d_out, int out_size, void* d_ws, size_t ws_size,
                              hipStream_t stream) {
  const float* x    = (const float*)d_in[0];  // (131072, 256) fp32
  const float* proj = (const float*)d_in[1];  // (256, 256) fp32
  const float* cw   = (const float*)d_in[2];  // (256,) fp32
  float* out = (float*)d_out;                 // (256, 65536) fp32

  u16* projT = (u16*)d_ws;                    // 128 KiB

  transpose_proj<<<256, 256, 0, stream>>>(proj, projT);
  fused_swe<<<256, 1024, 99328, stream>>>(x, projT, cw, out);
}